// Round 3
// baseline (166.106 us; speedup 1.0000x reference)
//
#include <hip/hip_runtime.h>

#define BSZ 64
#define SEQ 512
#define HD  768
#define TT  64    // topic/token list length
#define NROW 6    // 3 weight sets x 2 outputs
#define NTASK 129 // 1 cls + 64 topic + 64 token per batch
#define QPB  4    // block quarters per batch

// One fused kernel: 256 blocks (4 per batch) x 256 threads.
// Phase 1: stage domain vector (3 KB) into LDS.
// Phase 2: compute effective weights V[6][768] into LDS (weights L2-hot).
// Phase 3: 4 waves x ~8 tasks, processed 2-at-a-time for latency overlap.
__global__ __launch_bounds__(256) void fused_kernel(
    const float* __restrict__ hidden,     // [64,512,768]
    const float* __restrict__ Wsrc,       // [862,384]
    const float* __restrict__ Wtgt,       // [862,384]
    const float* __restrict__ W_cls,      // [2,6144]
    const float* __restrict__ b_cls,      // [2]
    const float* __restrict__ W_topic,    // [2,6144]
    const float* __restrict__ b_topic,    // [2]
    const float* __restrict__ W_token,    // [2,6144]
    const float* __restrict__ b_token,    // [2]
    const int*   __restrict__ source_ids, // [64]
    const int*   __restrict__ target_ids, // [64]
    const int*   __restrict__ topic_inds, // [64,64]
    const float* __restrict__ topic_mask, // [64,64]
    const int*   __restrict__ token_inds, // [64,64]
    const float* __restrict__ token_mask, // [64,64]
    float*       __restrict__ out)        // [128 + 8192 + 8192]
{
    __shared__ __align__(16) float dom[HD];
    __shared__ __align__(16) float V[NROW * HD];

    const int b   = blockIdx.x >> 2;   // batch
    const int q   = blockIdx.x & 3;    // quarter of the task list
    const int tid = threadIdx.x;

    // ---- phase 1: domain = concat(Wsrc[src], Wtgt[tgt]) ----
    const int sid = source_ids[b];
    const int tgt = target_ids[b];
    for (int j = tid; j < HD; j += 256)
        dom[j] = (j < 384) ? Wsrc[sid * 384 + j] : Wtgt[tgt * 384 + (j - 384)];
    __syncthreads();

    // ---- phase 2: V[r][m*8+c] = sum_a dom[m*8+a] * W_w[o][m*64+a*8+c] ----
    // 4608 elems / 256 threads = 18 iters. r is wave-uniform (768 % 64 == 0).
    for (int idx = tid; idx < NROW * HD; idx += 256) {
        const int r = idx / HD;
        const int d = idx - r * HD;
        const int w = r >> 1, o = r & 1;
        const float* Wp = (w == 0) ? W_cls : (w == 1) ? W_topic : W_token;
        const int m = d >> 3, c = d & 7;
        const float* wrow = Wp + o * 6144 + m * 64 + c;
        float acc = 0.f;
        #pragma unroll
        for (int a = 0; a < 8; ++a)
            acc = fmaf(dom[m * 8 + a], wrow[a * 8], acc);
        V[idx] = acc;
    }
    __syncthreads();

    // ---- phase 3: tasks, two per iteration ----
    const int wave = tid >> 6;
    const int lane = tid & 63;
    // quarters: [0,33) [33,65) [65,97) [97,129)
    const int tbase = (q == 0) ? 0 : 33 + 32 * (q - 1);
    const int tend  = (q == 0) ? 33 : tbase + 32;

    const float bc0 = b_cls[0],   bc1 = b_cls[1];
    const float bp0 = b_topic[0], bp1 = b_topic[1];
    const float bk0 = b_token[0], bk1 = b_token[1];

    for (int tA = tbase + wave; tA < tend; tA += 8) {
        const int tB = tA + 4;
        const bool hasB = (tB < tend);

        // decode both tasks
        int wA, posA, offA; float mA; bool smA;
        int wB = 0, posB = 0, offB = 0; float mB = 0.f; bool smB = false;
        {
            const int t = tA;
            if (t == 0) { wA = 0; posA = 0; mA = 1.f; smA = true; offA = b * 2; }
            else if (t <= TT) {
                const int l = t - 1;
                wA = 1; posA = topic_inds[b * TT + l]; mA = topic_mask[b * TT + l];
                smA = true; offA = 128 + (b * TT + l) * 2;
            } else {
                const int l = t - 1 - TT;
                wA = 2; posA = token_inds[b * TT + l]; mA = token_mask[b * TT + l];
                smA = false; offA = 128 + BSZ * TT * 2 + (b * TT + l) * 2;
            }
        }
        if (hasB) {
            const int t = tB;
            if (t <= TT) {
                const int l = t - 1;
                wB = 1; posB = topic_inds[b * TT + l]; mB = topic_mask[b * TT + l];
                smB = true; offB = 128 + (b * TT + l) * 2;
            } else {
                const int l = t - 1 - TT;
                wB = 2; posB = token_inds[b * TT + l]; mB = token_mask[b * TT + l];
                smB = false; offB = 128 + BSZ * TT * 2 + (b * TT + l) * 2;
            }
        }

        // issue all HBM loads for both tasks up front
        const float4* hA = reinterpret_cast<const float4*>(
            hidden + ((size_t)b * SEQ + (size_t)posA) * HD);
        const float4* hB = reinterpret_cast<const float4*>(
            hidden + ((size_t)b * SEQ + (size_t)posB) * HD);
        float4 ra0 = hA[lane], ra1 = hA[lane + 64], ra2 = hA[lane + 128];
        float4 rb0, rb1, rb2;
        if (hasB) { rb0 = hB[lane]; rb1 = hB[lane + 64]; rb2 = hB[lane + 128]; }

        const float4* vA0 = reinterpret_cast<const float4*>(&V[(wA * 2 + 0) * HD]);
        const float4* vA1 = reinterpret_cast<const float4*>(&V[(wA * 2 + 1) * HD]);
        const float4* vB0 = reinterpret_cast<const float4*>(&V[(wB * 2 + 0) * HD]);
        const float4* vB1 = reinterpret_cast<const float4*>(&V[(wB * 2 + 1) * HD]);

        float a0 = 0.f, a1 = 0.f, c0 = 0.f, c1 = 0.f;
        #define DOT(h4, x0, x1, A0, A1)                          \
            { A0 = fmaf(h4.x, x0.x, A0); A1 = fmaf(h4.x, x1.x, A1); \
              A0 = fmaf(h4.y, x0.y, A0); A1 = fmaf(h4.y, x1.y, A1); \
              A0 = fmaf(h4.z, x0.z, A0); A1 = fmaf(h4.z, x1.z, A1); \
              A0 = fmaf(h4.w, x0.w, A0); A1 = fmaf(h4.w, x1.w, A1); }
        {
            float4 x0, x1;
            x0 = vA0[lane];       x1 = vA1[lane];       DOT(ra0, x0, x1, a0, a1);
            x0 = vA0[lane + 64];  x1 = vA1[lane + 64];  DOT(ra1, x0, x1, a0, a1);
            x0 = vA0[lane + 128]; x1 = vA1[lane + 128]; DOT(ra2, x0, x1, a0, a1);
            if (hasB) {
                x0 = vB0[lane];       x1 = vB1[lane];       DOT(rb0, x0, x1, c0, c1);
                x0 = vB0[lane + 64];  x1 = vB1[lane + 64];  DOT(rb1, x0, x1, c0, c1);
                x0 = vB0[lane + 128]; x1 = vB1[lane + 128]; DOT(rb2, x0, x1, c0, c1);
            }
        }
        #undef DOT

        #pragma unroll
        for (int off = 32; off > 0; off >>= 1) {
            a0 += __shfl_down(a0, off, 64);
            a1 += __shfl_down(a1, off, 64);
            c0 += __shfl_down(c0, off, 64);
            c1 += __shfl_down(c1, off, 64);
        }

        if (lane == 0) {
            {
                const float bb0 = (wA == 0) ? bc0 : (wA == 1) ? bp0 : bk0;
                const float bb1 = (wA == 0) ? bc1 : (wA == 1) ? bp1 : bk1;
                const float l0 = fmaf(mA, a0, bb0);
                const float l1 = fmaf(mA, a1, bb1);
                if (smA) {
                    const float mx = fmaxf(l0, l1);
                    const float e0 = __expf(l0 - mx);
                    const float e1 = __expf(l1 - mx);
                    const float inv = 1.f / (e0 + e1);
                    out[offA] = e0 * inv; out[offA + 1] = e1 * inv;
                } else {
                    out[offA] = l0; out[offA + 1] = l1;
                }
            }
            if (hasB) {
                const float bb0 = (wB == 1) ? bp0 : bk0;
                const float bb1 = (wB == 1) ? bp1 : bk1;
                const float l0 = fmaf(mB, c0, bb0);
                const float l1 = fmaf(mB, c1, bb1);
                if (smB) {
                    const float mx = fmaxf(l0, l1);
                    const float e0 = __expf(l0 - mx);
                    const float e1 = __expf(l1 - mx);
                    const float inv = 1.f / (e0 + e1);
                    out[offB] = e0 * inv; out[offB + 1] = e1 * inv;
                } else {
                    out[offB] = l0; out[offB + 1] = l1;
                }
            }
        }
    }
}

extern "C" void kernel_launch(void* const* d_in, const int* in_sizes, int n_in,
                              void* d_out, int out_size, void* d_ws, size_t ws_size,
                              hipStream_t stream) {
    const float* hidden     = (const float*)d_in[0];
    const float* Wsrc       = (const float*)d_in[1];
    const float* Wtgt       = (const float*)d_in[2];
    const float* W_cls      = (const float*)d_in[3];
    const float* b_cls      = (const float*)d_in[4];
    const float* W_topic    = (const float*)d_in[5];
    const float* b_topic    = (const float*)d_in[6];
    const float* W_token    = (const float*)d_in[7];
    const float* b_token    = (const float*)d_in[8];
    const int*   source_ids = (const int*)d_in[9];
    const int*   target_ids = (const int*)d_in[10];
    // d_in[11] ent_inds, d_in[12] ent_mask: dead in reference (never used)
    const int*   topic_inds = (const int*)d_in[13];
    const float* topic_mask = (const float*)d_in[14];
    const int*   token_inds = (const int*)d_in[15];
    const float* token_mask = (const float*)d_in[16];
    float* out = (float*)d_out;

    fused_kernel<<<BSZ * QPB, 256, 0, stream>>>(
        hidden, Wsrc, Wtgt, W_cls, b_cls, W_topic, b_topic, W_token, b_token,
        source_ids, target_ids, topic_inds, topic_mask, token_inds, token_mask, out);
}